// Round 1
// baseline (855.282 us; speedup 1.0000x reference)
//
#include <hip/hip_runtime.h>

#define N_DIM 128
#define F_DIM 64

// ---------------- degree / sort kernels ----------------

__global__ __launch_bounds__(256) void k_count(const int* __restrict__ dst, int* __restrict__ cnt, int e) {
    int i = blockIdx.x * 256 + threadIdx.x;
    if (i < e) atomicAdd(&cnt[dst[i]], 1);
}

__global__ __launch_bounds__(256) void k_dinv(const int* __restrict__ cnt, float* __restrict__ dinv, int n) {
    int i = blockIdx.x * 256 + threadIdx.x;
    if (i < n) dinv[i] = rsqrtf((float)cnt[i] + 1.0f);   // +1 self loop
}

__global__ __launch_bounds__(256) void k_scan1(const int* __restrict__ cnt, int* __restrict__ excl,
                                               int* __restrict__ bsum, int n) {
    __shared__ int s[256];
    int t = threadIdx.x;
    int i = blockIdx.x * 256 + t;
    int v = (i < n) ? cnt[i] : 0;
    s[t] = v;
    __syncthreads();
    for (int off = 1; off < 256; off <<= 1) {
        int x = (t >= off) ? s[t - off] : 0;
        __syncthreads();
        s[t] += x;
        __syncthreads();
    }
    if (i < n) excl[i] = s[t] - v;
    if (t == 255) bsum[blockIdx.x] = s[255];
}

__global__ __launch_bounds__(512) void k_scan2(int* __restrict__ bsum, int nb, int* __restrict__ start, int n) {
    __shared__ int s[512];
    int t = threadIdx.x;
    int v = (t < nb) ? bsum[t] : 0;
    s[t] = v;
    __syncthreads();
    for (int off = 1; off < 512; off <<= 1) {
        int x = (t >= off) ? s[t - off] : 0;
        __syncthreads();
        s[t] += x;
        __syncthreads();
    }
    if (t < nb) bsum[t] = s[t] - v;     // exclusive block offsets
    if (t == 511) start[n] = s[511];    // total edge count
}

__global__ __launch_bounds__(256) void k_scan3(int* __restrict__ start, int* __restrict__ cursor,
                                               const int* __restrict__ bsum, int n) {
    int i = blockIdx.x * 256 + threadIdx.x;
    if (i < n) {
        int v = start[i] + bsum[blockIdx.x];
        start[i] = v;
        cursor[i] = v;
    }
}

__global__ __launch_bounds__(256) void k_place(const int* __restrict__ src, const int* __restrict__ dst,
                                               int* __restrict__ cursor, int* __restrict__ srcs, int e) {
    int i = blockIdx.x * 256 + threadIdx.x;
    if (i < e) {
        int slot = atomicAdd(&cursor[dst[i]], 1);
        srcs[slot] = src[i];
    }
}

// ---------------- GEMM kernels (vector f32, W in LDS, shfl-broadcast row) ----------------

// h = x @ W_pre + b_pre    (N x 128) @ (128 x 64)
__global__ __launch_bounds__(256) void k_gemm_pre(const float* __restrict__ X, const float* __restrict__ W,
                                                  const float* __restrict__ b, float* __restrict__ H, int n) {
    __shared__ float Wl[N_DIM * F_DIM];
    for (int i = threadIdx.x; i < N_DIM * F_DIM; i += 256) Wl[i] = W[i];
    __syncthreads();
    int lane = threadIdx.x & 63;
    int wave = threadIdx.x >> 6;
    const int ROWS = 4;
    int r0 = (blockIdx.x * 4 + wave) * ROWS;
    float bj = b[lane];
    for (int rr = 0; rr < ROWS; ++rr) {
        int r = r0 + rr;
        if (r >= n) break;
        float h0 = X[(size_t)r * N_DIM + lane];
        float h1 = X[(size_t)r * N_DIM + 64 + lane];
        float acc = bj;
#pragma unroll
        for (int k = 0; k < 64; ++k) acc = fmaf(__shfl(h0, k), Wl[k * 64 + lane], acc);
#pragma unroll
        for (int k = 0; k < 64; ++k) acc = fmaf(__shfl(h1, k), Wl[(64 + k) * 64 + lane], acc);
        H[(size_t)r * F_DIM + lane] = acc;
    }
}

// u = dinv * (h @ W)       (N x 64) @ (64 x 64), dinv folded in, no bias
__global__ __launch_bounds__(256) void k_gemm_l(const float* __restrict__ H, const float* __restrict__ W,
                                                const float* __restrict__ dinv, float* __restrict__ U, int n) {
    __shared__ float Wl[F_DIM * F_DIM];
    for (int i = threadIdx.x; i < F_DIM * F_DIM; i += 256) Wl[i] = W[i];
    __syncthreads();
    int lane = threadIdx.x & 63;
    int wave = threadIdx.x >> 6;
    const int ROWS = 8;
    int r0 = (blockIdx.x * 4 + wave) * ROWS;
    for (int rr = 0; rr < ROWS; ++rr) {
        int r = r0 + rr;
        if (r >= n) break;
        float hv = H[(size_t)r * F_DIM + lane];
        float acc = 0.0f;
#pragma unroll
        for (int k = 0; k < 64; ++k) acc = fmaf(__shfl(hv, k), Wl[k * 64 + lane], acc);
        U[(size_t)r * F_DIM + lane] = dinv[r] * acc;
    }
}

// ---------------- aggregation: out[i] = epilogue( dinv[i]*(u[i] + sum_{src->i} u[src]) + b ) ----------------
// MODE 0: relu -> H ; MODE 1: row L2-normalize -> d_out
template <int MODE>
__global__ __launch_bounds__(256) void k_agg(const float* __restrict__ U, const int* __restrict__ srcs,
                                             const int* __restrict__ start, const float* __restrict__ dinv,
                                             const float* __restrict__ bias, float* __restrict__ out, int n) {
    int wave = blockIdx.x * 4 + (threadIdx.x >> 6);
    int lane = threadIdx.x & 63;
    if (wave >= n) return;
    int i = wave;
    int s0 = start[i];
    int s1 = start[i + 1];
    float acc = U[(size_t)i * F_DIM + lane];  // self loop term
    for (int j = s0; j < s1; j += 64) {
        int cnt = min(64, s1 - j);
        int myidx = (lane < cnt) ? srcs[j + lane] : 0;
        int t = 0;
        for (; t + 4 <= cnt; t += 4) {
            int a0 = __shfl(myidx, t);
            int a1 = __shfl(myidx, t + 1);
            int a2 = __shfl(myidx, t + 2);
            int a3 = __shfl(myidx, t + 3);
            float v0 = U[(size_t)a0 * F_DIM + lane];
            float v1 = U[(size_t)a1 * F_DIM + lane];
            float v2 = U[(size_t)a2 * F_DIM + lane];
            float v3 = U[(size_t)a3 * F_DIM + lane];
            acc += v0;
            acc += v1;
            acc += v2;
            acc += v3;
        }
        for (; t < cnt; ++t) {
            int s = __shfl(myidx, t);
            acc += U[(size_t)s * F_DIM + lane];
        }
    }
    float v = dinv[i] * acc + bias[lane];
    if (MODE == 0) {
        out[(size_t)i * F_DIM + lane] = fmaxf(v, 0.0f);
    } else {
        float ss = v * v;
#pragma unroll
        for (int o = 1; o < 64; o <<= 1) ss += __shfl_xor(ss, o);
        float nrm = fmaxf(sqrtf(ss), 1e-12f);
        out[(size_t)i * F_DIM + lane] = v / nrm;
    }
}

// ---------------- launch ----------------

extern "C" void kernel_launch(void* const* d_in, const int* in_sizes, int n_in,
                              void* d_out, int out_size, void* d_ws, size_t ws_size,
                              hipStream_t stream) {
    const float* x     = (const float*)d_in[0];
    const int*   ei    = (const int*)d_in[1];
    const float* W_pre = (const float*)d_in[2];
    const float* b_pre = (const float*)d_in[3];
    const float* W1    = (const float*)d_in[4];
    const float* b1    = (const float*)d_in[5];
    const float* Wh    = (const float*)d_in[6];
    const float* bh    = (const float*)d_in[7];
    const float* Wo    = (const float*)d_in[8];
    const float* bo    = (const float*)d_in[9];

    int n = in_sizes[0] / N_DIM;   // 100000
    int e = in_sizes[1] / 2;       // 1600000
    const int* srcIdx = ei;
    const int* dstIdx = ei + e;

    // workspace carve-out
    size_t off = 0;
    auto alloc = [&](size_t bytes) -> void* {
        void* p = (char*)d_ws + off;
        off += (bytes + 255) & ~(size_t)255;
        return p;
    };
    int*   cnt    = (int*)alloc((size_t)n * 4);
    int*   start  = (int*)alloc((size_t)(n + 1) * 4);
    int*   cursor = (int*)alloc((size_t)n * 4);
    float* dinv   = (float*)alloc((size_t)n * 4);
    int*   bsum   = (int*)alloc(512 * 4);
    int*   srcs   = (int*)alloc((size_t)e * 4);
    float* h      = (float*)alloc((size_t)n * F_DIM * 4);
    float* u      = (float*)alloc((size_t)n * F_DIM * 4);

    int nbN = (n + 255) / 256;
    int nbE = (e + 255) / 256;

    // 1. degree count (without self loops)
    hipMemsetAsync(cnt, 0, (size_t)n * 4, stream);
    k_count<<<nbE, 256, 0, stream>>>(dstIdx, cnt, e);
    k_dinv<<<nbN, 256, 0, stream>>>(cnt, dinv, n);

    // 2. exclusive scan of counts -> start offsets, cursor copy
    k_scan1<<<nbN, 256, 0, stream>>>(cnt, start, bsum, n);
    k_scan2<<<1, 512, 0, stream>>>(bsum, nbN, start, n);
    k_scan3<<<nbN, 256, 0, stream>>>(start, cursor, bsum, n);

    // 3. place src indices sorted by dst
    k_place<<<nbE, 256, 0, stream>>>(srcIdx, dstIdx, cursor, srcs, e);

    // 4. feature_pre linear: h = x @ W_pre + b_pre
    k_gemm_pre<<<(n + 15) / 16, 256, 0, stream>>>(x, W_pre, b_pre, h, n);

    // 5. layer 1
    k_gemm_l<<<(n + 31) / 32, 256, 0, stream>>>(h, W1, dinv, u, n);
    k_agg<0><<<(n + 3) / 4, 256, 0, stream>>>(u, srcs, start, dinv, b1, h, n);

    // 6. layer 2
    k_gemm_l<<<(n + 31) / 32, 256, 0, stream>>>(h, Wh, dinv, u, n);
    k_agg<0><<<(n + 3) / 4, 256, 0, stream>>>(u, srcs, start, dinv, bh, h, n);

    // 7. layer 3 + final row L2 normalize -> d_out
    k_gemm_l<<<(n + 31) / 32, 256, 0, stream>>>(h, Wo, dinv, u, n);
    k_agg<1><<<(n + 3) / 4, 256, 0, stream>>>(u, srcs, start, dinv, bo, (float*)d_out, n);
}